// Round 1
// baseline (6833.388 us; speedup 1.0000x reference)
//
#include <hip/hip_runtime.h>
#include <hip/hip_bf16.h>

// EA-LSTM persistent kernel for MI355X (gfx950).
// B=128, T=2048, DYN=8, STAT=24, H=256, OUT=1.
// 8 workgroups x 512 threads (8 waves). WG wg owns batch rows [wg*16, wg*16+16).
// Wave w owns output-channel slice n in [w*32, w*32+32) for all gates (f,g,o,I)
// and keeps c-state for that slice in registers.
// Recurrent weights: K-steps 0..6 in VGPRs (bf16 MFMA fragments), K-step 7 and
// x-projection fragments in LDS. h_t exchanged via LDS, 2 barriers per step.

#define T_LEN 2048
#define HD 256

typedef __attribute__((ext_vector_type(8))) short bf16x8;
typedef __attribute__((ext_vector_type(4))) float f32x4;

#define LOG2E 1.4426950408889634f

__device__ __forceinline__ short f2bf(float f) {
  // round-to-nearest-even fp32 -> bf16
  unsigned u = __float_as_uint(f);
  unsigned r = (u + 0x7fffu + ((u >> 16) & 1u)) >> 16;
  return (short)r;
}

__device__ __forceinline__ bf16x8 loadw8(const float* p) {
  bf16x8 r;
#pragma unroll
  for (int i = 0; i < 8; ++i) r[i] = f2bf(p[i]);
  return r;
}

__device__ __forceinline__ float sigm(float x) {
  float e = __builtin_amdgcn_exp2f(-LOG2E * x);
  return __builtin_amdgcn_rcpf(1.0f + e);
}

__device__ __forceinline__ float tanh_(float x) {
  float xc = fminf(fmaxf(x, -15.0f), 15.0f);
  float e = __builtin_amdgcn_exp2f(2.0f * LOG2E * xc);
  return (e - 1.0f) * __builtin_amdgcn_rcpf(e + 1.0f);
}

// LDS A-buffer: 16 rows (batch) x 296 cols (bf16). cols 0..255 = h_{t-1},
// cols 256..287 = x_t (8 dyn + 24 stat), cols 288..295 pad.
// Row stride 296 shorts = 592 B = 37*16 -> 16B-aligned rows, 2-way-bank-free.
#define ASTR 296

// Per-wave LDS B-fragments (shorts):
//   [0,3072)        : 6 full frags (rec K-step 7: gate{f,g,o} x nt{0,1}), 512 shorts each
//   [3072,3840)     : 6 quarter frags (x-proj f,g,o; only lane-group 0 holds data), 128 shorts each
//   [3840,4608)     : 2 three-quarter frags (I gate; lane-groups 1..3), 384 shorts each
#define BWSTR 4608

__global__ __launch_bounds__(512, 2) void ealstm_kernel(
    const float* __restrict__ x, const float* __restrict__ c0, const float* __restrict__ h0,
    const float* __restrict__ Wi, const float* __restrict__ bi,
    const float* __restrict__ Wfx, const float* __restrict__ bfx,
    const float* __restrict__ Wfh, const float* __restrict__ bfh,
    const float* __restrict__ Wgx, const float* __restrict__ bgx,
    const float* __restrict__ Wgh, const float* __restrict__ bgh,
    const float* __restrict__ Wox, const float* __restrict__ box_,
    const float* __restrict__ Woh, const float* __restrict__ boh,
    const float* __restrict__ Wout, const float* __restrict__ bout,
    float* __restrict__ out)
{
  __shared__ __attribute__((aligned(16))) short A_sh[16 * ASTR];
  __shared__ __attribute__((aligned(16))) short B_sh[8 * BWSTR];
  __shared__ float out_part[8 * 16];

  const int tid = threadIdx.x;
  const int w   = tid >> 6;   // wave 0..7
  const int l   = tid & 63;   // lane
  const int lr  = l & 15;     // lane row/col within 16
  const int lg  = l >> 4;     // lane group 0..3
  const int n0  = w * 32;     // wave's n-slice base
  const int wg  = blockIdx.x; // batch block

  const float* WhArr[3] = {Wfh, Wgh, Woh};
  const float* WxArr[3] = {Wfx, Wgx, Wox};

  // ---- persistent register weight fragments: recurrent K-steps 0..6 ----
  // B-frag (16x16x32): lane l holds W[n0+nt*16+(l&15)][k0+(l>>4)*8 + i], i=0..7
  bf16x8 Bh[3][7][2];
#pragma unroll
  for (int g = 0; g < 3; ++g) {
#pragma unroll
    for (int ks = 0; ks < 7; ++ks) {
#pragma unroll
      for (int nt = 0; nt < 2; ++nt) {
        const int n = n0 + nt * 16 + lr;
        const int k = ks * 32 + lg * 8;
        Bh[g][ks][nt] = loadw8(WhArr[g] + n * HD + k);
      }
    }
  }

  // ---- LDS-resident fragments ----
  short* bsh = B_sh + w * BWSTR;
  {
    // recurrent K-step 7 (full frags)
#pragma unroll
    for (int g = 0; g < 3; ++g) {
#pragma unroll
      for (int nt = 0; nt < 2; ++nt) {
        const int n = n0 + nt * 16 + lr;
        bf16x8 fr = loadw8(WhArr[g] + n * HD + 7 * 32 + lg * 8);
        *reinterpret_cast<bf16x8*>(bsh + (g * 2 + nt) * 512 + l * 8) = fr;
      }
    }
    if (lg == 0) {
      // x-projection for f,g,o: K rows 0..7 of the x K-step (DYN=8 exactly)
#pragma unroll
      for (int g = 0; g < 3; ++g) {
#pragma unroll
        for (int nt = 0; nt < 2; ++nt) {
          const int n = n0 + nt * 16 + lr;
          bf16x8 fr = loadw8(WxArr[g] + n * 8);
          *reinterpret_cast<bf16x8*>(bsh + 3072 + (g * 2 + nt) * 128 + lr * 8) = fr;
        }
      }
    } else {
      // I gate: K rows 8..31 of the x K-step map to Wi[n][0..24) (STAT=24 exactly)
#pragma unroll
      for (int nt = 0; nt < 2; ++nt) {
        const int n = n0 + nt * 16 + lr;
        bf16x8 fr = loadw8(Wi + n * 24 + (lg - 1) * 8);
        *reinterpret_cast<bf16x8*>(bsh + 3840 + nt * 384 + (lg - 1) * 128 + lr * 8) = fr;
      }
    }
  }

  // ---- biases (combined), Wout, c-state init ----
  float bias[4][2], woutv[2];
  f32x4 cst[2];
#pragma unroll
  for (int nt = 0; nt < 2; ++nt) {
    const int n = n0 + nt * 16 + lr;
    bias[0][nt] = bfx[n] + bfh[n];
    bias[1][nt] = bgx[n] + bgh[n];
    bias[2][nt] = box_[n] + boh[n];
    bias[3][nt] = bi[n];
    woutv[nt] = Wout[n];
    const float c0v = c0[n];
    f32x4 cv; cv[0] = c0v; cv[1] = c0v; cv[2] = c0v; cv[3] = c0v;
    cst[nt] = cv;
  }
  const float boutv = bout[0];

  // ---- stage h0 (broadcast over batch rows) and x_0 ----
  for (int idx = tid; idx < 16 * 256; idx += 512) {
    A_sh[(idx >> 8) * ASTR + (idx & 255)] = f2bf(h0[idx & 255]);
  }
  {
    const int bl = tid >> 5, k = tid & 31;
    A_sh[bl * ASTR + 256 + k] = f2bf(x[((size_t)(wg * 16 + bl) * T_LEN + 0) * 32 + k]);
  }
  __syncthreads();

  const float* xp = x + (size_t)(wg * 16 + (tid >> 5)) * T_LEN * 32 + (tid & 31);
  float* outp = out + (size_t)(wg * 16 + lr) * T_LEN;
  const short* Arow = A_sh + lr * ASTR;  // A-frag: lane reads row (l&15)
  const int akoff = lg * 8;

  for (int t = 0; t < T_LEN; ++t) {
    // prefetch x_{t+1} (clamped; value consumed after barrier 1)
    const int tn = (t + 1 < T_LEN) ? (t + 1) : (T_LEN - 1);
    const float xval = xp[(size_t)tn * 32];

    // accumulators, initialized with biases (bias depends on n only -> splat over rows)
    f32x4 acc[4][2];
#pragma unroll
    for (int g = 0; g < 4; ++g) {
#pragma unroll
      for (int nt = 0; nt < 2; ++nt) {
        f32x4 v; v[0] = bias[g][nt]; v[1] = bias[g][nt]; v[2] = bias[g][nt]; v[3] = bias[g][nt];
        acc[g][nt] = v;
      }
    }

    // recurrent MFMAs, K-steps 0..6 (register-resident B)
#pragma unroll
    for (int ks = 0; ks < 7; ++ks) {
      const bf16x8 a = *reinterpret_cast<const bf16x8*>(Arow + ks * 32 + akoff);
#pragma unroll
      for (int g = 0; g < 3; ++g) {
#pragma unroll
        for (int nt = 0; nt < 2; ++nt) {
          acc[g][nt] = __builtin_amdgcn_mfma_f32_16x16x32_bf16(a, Bh[g][ks][nt], acc[g][nt], 0, 0, 0);
        }
      }
    }
    // recurrent K-step 7 (LDS-resident B)
    {
      const bf16x8 a = *reinterpret_cast<const bf16x8*>(Arow + 7 * 32 + akoff);
#pragma unroll
      for (int g = 0; g < 3; ++g) {
#pragma unroll
        for (int nt = 0; nt < 2; ++nt) {
          const bf16x8 b = *reinterpret_cast<const bf16x8*>(bsh + (g * 2 + nt) * 512 + l * 8);
          acc[g][nt] = __builtin_amdgcn_mfma_f32_16x16x32_bf16(a, b, acc[g][nt], 0, 0, 0);
        }
      }
    }
    // x K-step: A cols 256..287 hold x_t
    {
      const bf16x8 ax = *reinterpret_cast<const bf16x8*>(Arow + 256 + akoff);
      bf16x8 z = (bf16x8)(short)0;
#pragma unroll
      for (int g = 0; g < 3; ++g) {
#pragma unroll
        for (int nt = 0; nt < 2; ++nt) {
          bf16x8 b = z;
          if (lg == 0) b = *reinterpret_cast<const bf16x8*>(bsh + 3072 + (g * 2 + nt) * 128 + lr * 8);
          acc[g][nt] = __builtin_amdgcn_mfma_f32_16x16x32_bf16(ax, b, acc[g][nt], 0, 0, 0);
        }
      }
#pragma unroll
      for (int nt = 0; nt < 2; ++nt) {
        bf16x8 b = z;
        if (lg >= 1) b = *reinterpret_cast<const bf16x8*>(bsh + 3840 + nt * 384 + (lg - 1) * 128 + lr * 8);
        acc[3][nt] = __builtin_amdgcn_mfma_f32_16x16x32_bf16(ax, b, acc[3][nt], 0, 0, 0);
      }
    }

    // ---- activations, state update, output partials ----
    // D layout: col n = n0+nt*16+(l&15), row m = (l>>4)*4 + r
    short hpk[2][4];
    f32x4 po; po[0] = 0.f; po[1] = 0.f; po[2] = 0.f; po[3] = 0.f;
#pragma unroll
    for (int nt = 0; nt < 2; ++nt) {
#pragma unroll
      for (int r = 0; r < 4; ++r) {
        const float fv = sigm(acc[0][nt][r]);
        const float gv = tanh_(acc[1][nt][r]);
        const float ov = sigm(acc[2][nt][r]);
        const float iv = sigm(acc[3][nt][r]);
        float c = fv * cst[nt][r] + iv * gv;
        cst[nt][r] = c;
        const float hv = ov * tanh_(c);
        hpk[nt][r] = f2bf(hv);
        po[r] += ov * woutv[nt];
      }
    }
    // reduce po over the 16 n-lanes within each lane group
#pragma unroll
    for (int r = 0; r < 4; ++r) {
#pragma unroll
      for (int mk = 1; mk < 16; mk <<= 1) {
        po[r] += __shfl_xor(po[r], mk, 64);
      }
    }

    __syncthreads();  // barrier 1: all reads of h_{t-1}/x_t done

    // write h_t into A_sh cols [n0, n0+32)
#pragma unroll
    for (int nt = 0; nt < 2; ++nt) {
#pragma unroll
      for (int r = 0; r < 4; ++r) {
        A_sh[(lg * 4 + r) * ASTR + (n0 + nt * 16 + lr)] = hpk[nt][r];
      }
    }
    // write x_{t+1} into A_sh cols 256..287
    A_sh[(tid >> 5) * ASTR + 256 + (tid & 31)] = f2bf(xval);
    // write output partials
    if (lr == 0) {
#pragma unroll
      for (int r = 0; r < 4; ++r) out_part[w * 16 + lg * 4 + r] = po[r];
    }

    __syncthreads();  // barrier 2: h_t / x_{t+1} / partials visible

    // final output reduce + store (wave 0, lanes 0..15), overlaps next step's MFMAs
    if (w == 0 && l < 16) {
      float s = boutv;
#pragma unroll
      for (int ww = 0; ww < 8; ++ww) s += out_part[ww * 16 + l];
      outp[t] = s;
    }
  }
}

extern "C" void kernel_launch(void* const* d_in, const int* in_sizes, int n_in,
                              void* d_out, int out_size, void* d_ws, size_t ws_size,
                              hipStream_t stream) {
  const float* x    = (const float*)d_in[0];
  const float* c0   = (const float*)d_in[1];
  const float* h0   = (const float*)d_in[2];
  const float* Wi   = (const float*)d_in[3];
  const float* bi   = (const float*)d_in[4];
  const float* Wfx  = (const float*)d_in[5];
  const float* bfx  = (const float*)d_in[6];
  const float* Wfh  = (const float*)d_in[7];
  const float* bfh  = (const float*)d_in[8];
  const float* Wgx  = (const float*)d_in[9];
  const float* bgx  = (const float*)d_in[10];
  const float* Wgh  = (const float*)d_in[11];
  const float* bgh  = (const float*)d_in[12];
  const float* Wox  = (const float*)d_in[13];
  const float* box_ = (const float*)d_in[14];
  const float* Woh  = (const float*)d_in[15];
  const float* boh  = (const float*)d_in[16];
  const float* Wout = (const float*)d_in[17];
  const float* bout = (const float*)d_in[18];

  ealstm_kernel<<<dim3(8), dim3(512), 0, stream>>>(
      x, c0, h0, Wi, bi, Wfx, bfx, Wfh, bfh,
      Wgx, bgx, Wgh, bgh, Wox, box_, Woh, boh, Wout, bout,
      (float*)d_out);
}

// Round 2
// 5152.649 us; speedup vs baseline: 1.3262x; 1.3262x over previous
//
#include <hip/hip_runtime.h>
#include <hip/hip_bf16.h>

// EA-LSTM persistent kernel for MI355X (gfx950), round 2.
// B=128, T=2048, DYN=8, STAT=24, H=256, OUT=1.
// 8 WGs x 512 threads (8 waves). WG owns 16 batch rows; wave w owns n-slice
// [w*32, w*32+32) of all 4 gates. Register budget discipline:
//   regs: f,g gates all 8 K-steps + o K-step 7  (34 frags = 136 VGPR)
//   LDS : o K-steps 0..6 (14 frags/wave = 112 KB) + x-proj frags + A double-buf
// Double-buffered A tile -> ONE barrier per step.

#define T_LEN 2048
#define HD 256

typedef __attribute__((ext_vector_type(8))) short bf16x8;
typedef __attribute__((ext_vector_type(4))) float f32x4;

#define LOG2E 1.4426950408889634f

__device__ __forceinline__ short f2bf(float f) {
  unsigned u = __float_as_uint(f);
  unsigned r = (u + 0x7fffu + ((u >> 16) & 1u)) >> 16;
  return (short)r;
}

__device__ __forceinline__ bf16x8 loadw8(const float* p) {
  bf16x8 r;
#pragma unroll
  for (int i = 0; i < 8; ++i) r[i] = f2bf(p[i]);
  return r;
}

__device__ __forceinline__ float sigm(float x) {
  float e = __builtin_amdgcn_exp2f(-LOG2E * x);
  return __builtin_amdgcn_rcpf(1.0f + e);
}

__device__ __forceinline__ float tanh_(float x) {
  float xc = fminf(fmaxf(x, -15.0f), 15.0f);
  float e = __builtin_amdgcn_exp2f(2.0f * LOG2E * xc);
  return (e - 1.0f) * __builtin_amdgcn_rcpf(e + 1.0f);
}

// A tile: 16 rows x 296 cols bf16 (cols 0..255 = h, 256..287 = x, 288+ pad).
// Row stride 296 shorts = 592 B (16B aligned; stride 148 dwords = 20 mod 32 -> 2-way banks).
#define ASTR 296
#define ABUF (16 * ASTR)

__global__ __launch_bounds__(512, 2) void ealstm_kernel(
    const float* __restrict__ x, const float* __restrict__ c0, const float* __restrict__ h0,
    const float* __restrict__ Wi, const float* __restrict__ bi,
    const float* __restrict__ Wfx, const float* __restrict__ bfx,
    const float* __restrict__ Wfh, const float* __restrict__ bfh,
    const float* __restrict__ Wgx, const float* __restrict__ bgx,
    const float* __restrict__ Wgh, const float* __restrict__ bgh,
    const float* __restrict__ Wox, const float* __restrict__ box_,
    const float* __restrict__ Woh, const float* __restrict__ boh,
    const float* __restrict__ Wout, const float* __restrict__ bout,
    float* __restrict__ out)
{
  __shared__ __attribute__((aligned(16))) short A_sh[2 * ABUF];            // 18944 B
  __shared__ __attribute__((aligned(16))) short Bo_sh[8 * 14 * 512];       // 114688 B
  __shared__ __attribute__((aligned(16))) short Bx_sh[8 * 1536];           // 24576 B
  __shared__ float out_part[2][128];                                       // 1024 B

  const int tid = threadIdx.x;
  const int w   = tid >> 6;
  const int l   = tid & 63;
  const int lr  = l & 15;
  const int lg  = l >> 4;
  const int n0  = w * 32;
  const int wg  = blockIdx.x;

  // ---- register-resident weight fragments: f,g all K-steps; o K-step 7 ----
  bf16x8 Bf[8][2], Bg[8][2], Bo7[2];
#pragma unroll
  for (int ks = 0; ks < 8; ++ks) {
#pragma unroll
    for (int nt = 0; nt < 2; ++nt) {
      const int n = n0 + nt * 16 + lr;
      const int k = ks * 32 + lg * 8;
      Bf[ks][nt] = loadw8(Wfh + n * HD + k);
      Bg[ks][nt] = loadw8(Wgh + n * HD + k);
    }
  }
#pragma unroll
  for (int nt = 0; nt < 2; ++nt) {
    const int n = n0 + nt * 16 + lr;
    Bo7[nt] = loadw8(Woh + n * HD + 7 * 32 + lg * 8);
  }

  // ---- LDS-resident: o K-steps 0..6 + x-projection frags ----
  short* bo = Bo_sh + w * (14 * 512);
#pragma unroll
  for (int ks = 0; ks < 7; ++ks) {
#pragma unroll
    for (int nt = 0; nt < 2; ++nt) {
      const int n = n0 + nt * 16 + lr;
      bf16x8 fr = loadw8(Woh + n * HD + ks * 32 + lg * 8);
      *reinterpret_cast<bf16x8*>(bo + (ks * 2 + nt) * 512 + l * 8) = fr;
    }
  }
  short* bx = Bx_sh + w * 1536;
  {
    const float* WxArr[3] = {Wfx, Wgx, Wox};
    if (lg == 0) {
#pragma unroll
      for (int g = 0; g < 3; ++g) {
#pragma unroll
        for (int nt = 0; nt < 2; ++nt) {
          const int n = n0 + nt * 16 + lr;
          bf16x8 fr = loadw8(WxArr[g] + n * 8);
          *reinterpret_cast<bf16x8*>(bx + (g * 2 + nt) * 128 + lr * 8) = fr;
        }
      }
    } else {
#pragma unroll
      for (int nt = 0; nt < 2; ++nt) {
        const int n = n0 + nt * 16 + lr;
        bf16x8 fr = loadw8(Wi + n * 24 + (lg - 1) * 8);
        *reinterpret_cast<bf16x8*>(bx + 768 + nt * 384 + (lg - 1) * 128 + lr * 8) = fr;
      }
    }
  }

  // ---- biases, Wout, c-state ----
  float bias[4][2], woutv[2];
  f32x4 cst[2];
#pragma unroll
  for (int nt = 0; nt < 2; ++nt) {
    const int n = n0 + nt * 16 + lr;
    bias[0][nt] = bfx[n] + bfh[n];
    bias[1][nt] = bgx[n] + bgh[n];
    bias[2][nt] = box_[n] + boh[n];
    bias[3][nt] = bi[n];
    woutv[nt] = Wout[n];
    const float c0v = c0[n];
    f32x4 cv; cv[0] = c0v; cv[1] = c0v; cv[2] = c0v; cv[3] = c0v;
    cst[nt] = cv;
  }
  const float boutv = bout[0];

  // ---- stage h0 and x_0 into buffer 0 ----
  for (int idx = tid; idx < 16 * 256; idx += 512) {
    A_sh[(idx >> 8) * ASTR + (idx & 255)] = f2bf(h0[idx & 255]);
  }
  {
    const int bl = tid >> 5, k = tid & 31;
    A_sh[bl * ASTR + 256 + k] = f2bf(x[((size_t)(wg * 16 + bl) * T_LEN + 0) * 32 + k]);
  }
  __syncthreads();

  const float* xp = x + (size_t)(wg * 16 + (tid >> 5)) * T_LEN * 32 + (tid & 31);
  float* outp = out + (size_t)(wg * 16 + lr) * T_LEN;
  const int akoff = lg * 8;

  for (int t = 0; t < T_LEN; ++t) {
    const int cur = t & 1;
    const short* Arow = A_sh + cur * ABUF + lr * ASTR;
    short* Anxt = A_sh + (cur ^ 1) * ABUF;

    // finalize previous step's output (shadow of this step's MFMAs)
    if (t > 0 && w == 0 && l < 16) {
      float s = boutv;
#pragma unroll
      for (int ww = 0; ww < 8; ++ww) s += out_part[cur ^ 1][ww * 16 + l];
      outp[t - 1] = s;
    }

    // prefetch x_{t+1}
    const int tn = (t + 1 < T_LEN) ? (t + 1) : (T_LEN - 1);
    const float xval = xp[(size_t)tn * 32];

    // acc init with biases
    f32x4 acc[4][2];
#pragma unroll
    for (int g = 0; g < 4; ++g) {
#pragma unroll
      for (int nt = 0; nt < 2; ++nt) {
        f32x4 v; v[0] = bias[g][nt]; v[1] = bias[g][nt]; v[2] = bias[g][nt]; v[3] = bias[g][nt];
        acc[g][nt] = v;
      }
    }

    // x K-step (LDS-resident B, masked by lane group)
    {
      const bf16x8 ax = *reinterpret_cast<const bf16x8*>(Arow + 256 + akoff);
      bf16x8 z = (bf16x8)(short)0;
#pragma unroll
      for (int g = 0; g < 3; ++g) {
#pragma unroll
        for (int nt = 0; nt < 2; ++nt) {
          bf16x8 b = z;
          if (lg == 0) b = *reinterpret_cast<const bf16x8*>(bx + (g * 2 + nt) * 128 + lr * 8);
          acc[g][nt] = __builtin_amdgcn_mfma_f32_16x16x32_bf16(ax, b, acc[g][nt], 0, 0, 0);
        }
      }
#pragma unroll
      for (int nt = 0; nt < 2; ++nt) {
        bf16x8 b = z;
        if (lg >= 1) b = *reinterpret_cast<const bf16x8*>(bx + 768 + nt * 384 + (lg - 1) * 128 + lr * 8);
        acc[3][nt] = __builtin_amdgcn_mfma_f32_16x16x32_bf16(ax, b, acc[3][nt], 0, 0, 0);
      }
    }

    // recurrent K-steps 0..6: f,g from regs; o from LDS
#pragma unroll
    for (int ks = 0; ks < 7; ++ks) {
      const bf16x8 a = *reinterpret_cast<const bf16x8*>(Arow + ks * 32 + akoff);
#pragma unroll
      for (int nt = 0; nt < 2; ++nt) {
        acc[0][nt] = __builtin_amdgcn_mfma_f32_16x16x32_bf16(a, Bf[ks][nt], acc[0][nt], 0, 0, 0);
        acc[1][nt] = __builtin_amdgcn_mfma_f32_16x16x32_bf16(a, Bg[ks][nt], acc[1][nt], 0, 0, 0);
        const bf16x8 b = *reinterpret_cast<const bf16x8*>(bo + (ks * 2 + nt) * 512 + l * 8);
        acc[2][nt] = __builtin_amdgcn_mfma_f32_16x16x32_bf16(a, b, acc[2][nt], 0, 0, 0);
      }
    }
    // K-step 7: all from regs
    {
      const bf16x8 a = *reinterpret_cast<const bf16x8*>(Arow + 7 * 32 + akoff);
#pragma unroll
      for (int nt = 0; nt < 2; ++nt) {
        acc[0][nt] = __builtin_amdgcn_mfma_f32_16x16x32_bf16(a, Bf[7][nt], acc[0][nt], 0, 0, 0);
        acc[1][nt] = __builtin_amdgcn_mfma_f32_16x16x32_bf16(a, Bg[7][nt], acc[1][nt], 0, 0, 0);
        acc[2][nt] = __builtin_amdgcn_mfma_f32_16x16x32_bf16(a, Bo7[nt], acc[2][nt], 0, 0, 0);
      }
    }

    // ---- activations + state update + output partials ----
    short hpk[2][4];
    f32x4 po; po[0] = 0.f; po[1] = 0.f; po[2] = 0.f; po[3] = 0.f;
#pragma unroll
    for (int nt = 0; nt < 2; ++nt) {
#pragma unroll
      for (int r = 0; r < 4; ++r) {
        const float fv = sigm(acc[0][nt][r]);
        const float gv = tanh_(acc[1][nt][r]);
        const float ov = sigm(acc[2][nt][r]);
        const float iv = sigm(acc[3][nt][r]);
        float c = fv * cst[nt][r] + iv * gv;
        cst[nt][r] = c;
        const float hv = ov * tanh_(c);
        hpk[nt][r] = f2bf(hv);
        po[r] += ov * woutv[nt];
      }
    }
#pragma unroll
    for (int r = 0; r < 4; ++r) {
#pragma unroll
      for (int mk = 1; mk < 16; mk <<= 1) {
        po[r] += __shfl_xor(po[r], mk, 64);
      }
    }

    // writes into the ALTERNATE buffer (no barrier needed before)
#pragma unroll
    for (int nt = 0; nt < 2; ++nt) {
#pragma unroll
      for (int r = 0; r < 4; ++r) {
        Anxt[(lg * 4 + r) * ASTR + (n0 + nt * 16 + lr)] = hpk[nt][r];
      }
    }
    Anxt[(tid >> 5) * ASTR + 256 + (tid & 31)] = f2bf(xval);
    if (lr == 0) {
#pragma unroll
      for (int r = 0; r < 4; ++r) out_part[cur][w * 16 + lg * 4 + r] = po[r];
    }

    __syncthreads();  // the single per-step barrier
  }

  // final output
  if (w == 0 && l < 16) {
    float s = boutv;
#pragma unroll
    for (int ww = 0; ww < 8; ++ww) s += out_part[(T_LEN - 1) & 1][ww * 16 + l];
    outp[T_LEN - 1] = s;
  }
}

extern "C" void kernel_launch(void* const* d_in, const int* in_sizes, int n_in,
                              void* d_out, int out_size, void* d_ws, size_t ws_size,
                              hipStream_t stream) {
  const float* x    = (const float*)d_in[0];
  const float* c0   = (const float*)d_in[1];
  const float* h0   = (const float*)d_in[2];
  const float* Wi   = (const float*)d_in[3];
  const float* bi   = (const float*)d_in[4];
  const float* Wfx  = (const float*)d_in[5];
  const float* bfx  = (const float*)d_in[6];
  const float* Wfh  = (const float*)d_in[7];
  const float* bfh  = (const float*)d_in[8];
  const float* Wgx  = (const float*)d_in[9];
  const float* bgx  = (const float*)d_in[10];
  const float* Wgh  = (const float*)d_in[11];
  const float* bgh  = (const float*)d_in[12];
  const float* Wox  = (const float*)d_in[13];
  const float* box_ = (const float*)d_in[14];
  const float* Woh  = (const float*)d_in[15];
  const float* boh  = (const float*)d_in[16];
  const float* Wout = (const float*)d_in[17];
  const float* bout = (const float*)d_in[18];

  ealstm_kernel<<<dim3(8), dim3(512), 0, stream>>>(
      x, c0, h0, Wi, bi, Wfx, bfx, Wfh, bfh,
      Wgx, bgx, Wgh, bgh, Wox, box_, Woh, boh, Wout, bout,
      (float*)d_out);
}